// Round 5
// baseline (165.273 us; speedup 1.0000x reference)
//
#include <hip/hip_runtime.h>
#include <stdint.h>

#define SEQ 8192
#define DIN 768
#define DOUT 128

typedef __attribute__((ext_vector_type(8))) short short8;
typedef __attribute__((ext_vector_type(8))) unsigned short ushort8v;
typedef __attribute__((ext_vector_type(4))) float f32x4;

// softmax exp base conversion: (1/sqrt(128)) * log2(e), folded into x for the Q proj
#define CEXPF (1.4426950408889634f * 0.08838834764831845f)

#if __has_builtin(__builtin_amdgcn_exp2f)
#define EXP2(x) __builtin_amdgcn_exp2f(x)
#else
#define EXP2(x) __builtin_exp2f(x)
#endif

// round-half-up f32->bf16 (2 VALU ops)
__device__ __forceinline__ unsigned short f2bf(float f) {
  return (unsigned short)((__float_as_uint(f) + 0x8000u) >> 16);
}

// async global->LDS DMA, 16B per lane; consecutive lanes -> consecutive 16B.
__device__ __forceinline__ void gload_lds16(const void* g, void* l) {
  __builtin_amdgcn_global_load_lds(
      (const __attribute__((address_space(1))) void*)g,
      (__attribute__((address_space(3))) void*)l, 16, 0, 0);
}

// ---------------------------------------------------------------------------
// Kernel A: QKV projection with fused fp32->bf16 conversion (no conv kernel).
// grid (64, 3), block 256 (4 waves).  Tile 128 seq x 128 outcol, BK=64.
// Staging: each thread loads 32 fp32 of x and W, converts, writes 4 XOR-chunked
// b128 to LDS.  z=0 scales x by CEXPF (softmax scale folded into Q).
// A=W (m=outcol), B=x (n=seqrow) -> packed ushort4 epilogue; z=2 -> Vt.
// ---------------------------------------------------------------------------
__launch_bounds__(256, 2)
__global__ void qkv_kernel(const float* __restrict__ x,
                           const float* __restrict__ wq,
                           const float* __restrict__ wk,
                           const float* __restrict__ wvp,
                           unsigned short* __restrict__ Qb,
                           unsigned short* __restrict__ Kb,
                           unsigned short* __restrict__ Vtb) {
  __shared__ unsigned char lds_u[34816];   // xs 16K + ws 16K; reused as ct[128][136]
  unsigned char* xs = lds_u;               // [128 seqrow][8 chunks] XOR-swizzled
  unsigned char* ws = lds_u + 16384;       // [128 outcol][8 chunks]

  const int t    = threadIdx.x;
  const int w    = t >> 6;
  const int lane = t & 63;
  const int g    = lane >> 4;
  const int r    = lane & 15;
  const int z    = blockIdx.y;
  const int m0   = blockIdx.x * 128;
  const float* W = (z == 0) ? wq : (z == 1) ? wk : wvp;
  const float xsc = (z == 0) ? CEXPF : 1.0f;

  f32x4 acc[2][8];
#pragma unroll
  for (int i = 0; i < 2; i++)
#pragma unroll
    for (int j = 0; j < 8; j++) acc[i][j] = 0.f;

  const int trow = t >> 1;        // 0..127
  const int cb   = (t & 1) * 4;   // chunk base 0 / 4

#pragma unroll 1
  for (int kb = 0; kb < DIN; kb += 64) {
    const float* xsrc = x + (size_t)(m0 + trow) * DIN + kb + cb * 8;
    const float* wsrc = W + (size_t)trow * DIN + kb + cb * 8;
    float4 xv[8], wv[8];
#pragma unroll
    for (int i = 0; i < 8; i++) {
      xv[i] = *(const float4*)(xsrc + i * 4);
      wv[i] = *(const float4*)(wsrc + i * 4);
    }
    __syncthreads();   // prior iter's frag reads done before we overwrite
#pragma unroll
    for (int c = 0; c < 4; c++) {
      ushort8v xo, wo;
#pragma unroll
      for (int h = 0; h < 2; h++) {
        xo[h * 4 + 0] = f2bf(xv[c * 2 + h].x * xsc);
        xo[h * 4 + 1] = f2bf(xv[c * 2 + h].y * xsc);
        xo[h * 4 + 2] = f2bf(xv[c * 2 + h].z * xsc);
        xo[h * 4 + 3] = f2bf(xv[c * 2 + h].w * xsc);
        wo[h * 4 + 0] = f2bf(wv[c * 2 + h].x);
        wo[h * 4 + 1] = f2bf(wv[c * 2 + h].y);
        wo[h * 4 + 2] = f2bf(wv[c * 2 + h].z);
        wo[h * 4 + 3] = f2bf(wv[c * 2 + h].w);
      }
      int ch = (cb + c) ^ (trow & 7);
      *(ushort8v*)(xs + trow * 128 + ch * 16) = xo;
      *(ushort8v*)(ws + trow * 128 + ch * 16) = wo;
    }
    __syncthreads();

    short8 af[2][2], bf[2];
#pragma unroll
    for (int mt = 0; mt < 2; mt++)
#pragma unroll
      for (int kc = 0; kc < 2; kc++) {
        int row = w * 32 + mt * 16 + r;
        af[mt][kc] = *(const short8*)(ws + row * 128 + (((kc * 4 + g) ^ (r & 7)) << 4));
      }
#pragma unroll
    for (int nt = 0; nt < 8; nt++) {
      int row = nt * 16 + r;
#pragma unroll
      for (int kc = 0; kc < 2; kc++)
        bf[kc] = *(const short8*)(xs + row * 128 + (((kc * 4 + g) ^ (r & 7)) << 4));
#pragma unroll
      for (int mt = 0; mt < 2; mt++) {
        acc[mt][nt] = __builtin_amdgcn_mfma_f32_16x16x32_bf16(af[mt][0], bf[0], acc[mt][nt], 0, 0, 0);
        acc[mt][nt] = __builtin_amdgcn_mfma_f32_16x16x32_bf16(af[mt][1], bf[1], acc[mt][nt], 0, 0, 0);
      }
    }
  }
  __syncthreads();   // all frag reads done before ct reuse / exit

  // D[m = w*32+mt*16+g*4+reg (outcol)][n = nt*16+r (seqrow)]
  if (z < 2) {
    unsigned short* out = (z == 0) ? Qb : Kb;
#pragma unroll
    for (int mt = 0; mt < 2; mt++)
#pragma unroll
      for (int nt = 0; nt < 8; nt++) {
        ushort4 o;
        o.x = f2bf(acc[mt][nt][0]); o.y = f2bf(acc[mt][nt][1]);
        o.z = f2bf(acc[mt][nt][2]); o.w = f2bf(acc[mt][nt][3]);
        *(ushort4*)(out + (size_t)(m0 + nt * 16 + r) * DOUT + w * 32 + mt * 16 + g * 4) = o;
      }
  } else {
    unsigned short* ct = (unsigned short*)lds_u;   // [128 seqrow][136]
#pragma unroll
    for (int mt = 0; mt < 2; mt++)
#pragma unroll
      for (int nt = 0; nt < 8; nt++) {
        ushort4 o;
        o.x = f2bf(acc[mt][nt][0]); o.y = f2bf(acc[mt][nt][1]);
        o.z = f2bf(acc[mt][nt][2]); o.w = f2bf(acc[mt][nt][3]);
        *(ushort4*)&ct[(nt * 16 + r) * 136 + w * 32 + mt * 16 + g * 4] = o;
      }
    __syncthreads();
    int col  = t >> 1;            // outcol 0..127
    int half = (t & 1) * 64;      // seqrow half
#pragma unroll
    for (int h = 0; h < 8; h++) {
      ushort8v a;
#pragma unroll
      for (int i = 0; i < 8; i++) a[i] = ct[(half + h * 8 + i) * 136 + col];
      *(ushort8v*)(Vtb + (size_t)col * SEQ + m0 + half + h * 8) = a;
    }
  }
}

// ---------------------------------------------------------------------------
// Kernel B: flash attention (no online max; scale folded into Q).
// grid (64 qblocks, 8 splits), block 128 = 2 waves, wave = 64 q-rows, BN=64.
// Halved wave-redundancy vs 4x32q: each K/V LDS byte read by 2 waves not 4.
// P per-wave [64 q][64 kv] bf16, 16B-chunk XOR layout.
// ---------------------------------------------------------------------------
__launch_bounds__(128, 1)
__global__ void attn_kernel(const unsigned short* __restrict__ Qb,
                            const unsigned short* __restrict__ Kb,
                            const unsigned short* __restrict__ Vtb,
                            float* __restrict__ Opart,
                            float* __restrict__ lpart) {
  __shared__ unsigned char lds[49152];
  unsigned char* Kl = lds;           // [64 kv][128 k] bf16, chunks ^(row&15)
  unsigned char* Vl = lds + 16384;   // [128 d][64 kv] bf16, chunks ^(d&7)

  const int t    = threadIdx.x;
  const int wave = t >> 6;
  const int lane = t & 63;
  const int g    = lane >> 4;
  const int r    = lane & 15;
  unsigned char* Pl = lds + 32768 + wave * 8192;   // [64 q][64 kv] bf16 XOR-chunk

  const int qb = blockIdx.x;
  const int sp = blockIdx.y;
  const int q0 = qb * 128 + wave * 64;

  // Q B-frags (pre-scaled): n=r -> q, k=kc*32+g*8+j
  short8 qf[4][4];
#pragma unroll
  for (int nt = 0; nt < 4; nt++)
#pragma unroll
    for (int kc = 0; kc < 4; kc++)
      qf[nt][kc] = *(const short8*)(Qb + (size_t)(q0 + nt * 16 + r) * DOUT + kc * 32 + g * 8);

  short8 onesf;
#pragma unroll
  for (int j = 0; j < 8; j++) onesf[j] = (r == 0) ? (short)0x3F80 : (short)0;

  f32x4 oacc[4][8];
  f32x4 lacc[4];
#pragma unroll
  for (int nt = 0; nt < 4; nt++) {
    lacc[nt] = 0.f;
#pragma unroll
    for (int d = 0; d < 8; d++) oacc[nt][d] = 0.f;
  }

#pragma unroll 1
  for (int it = 0; it < 16; it++) {
    const int kv0 = sp * 1024 + it * 64;
    // ---- DMA staging (128 threads: 8 chunks each for K and V) ----
#pragma unroll
    for (int c = 0; c < 8; c++) {
      int idx = (wave * 8 + c) * 64 + lane;        // 0..1023
      int krow = idx >> 4, kch = idx & 15;
      gload_lds16(Kb + ((size_t)(kv0 + krow) << 7) + ((kch ^ (krow & 15)) << 3),
                  Kl + ((wave * 8 + c) << 10) + (lane << 4));
      int d = idx >> 3, c2 = idx & 7;
      gload_lds16(Vtb + (size_t)d * SEQ + kv0 + ((c2 ^ (d & 7)) << 3),
                  Vl + ((wave * 8 + c) << 10) + (lane << 4));
    }
    __syncthreads();

    // ---- S^T = K Q^T : A=kf (m=kv 64), B=qf (n=q 64) ----
    f32x4 sf[4][4];
#pragma unroll
    for (int mt = 0; mt < 4; mt++)
#pragma unroll
      for (int nt = 0; nt < 4; nt++) sf[mt][nt] = 0.f;
#pragma unroll
    for (int mt = 0; mt < 4; mt++) {
      int row = mt * 16 + r;
#pragma unroll
      for (int kc = 0; kc < 4; kc++) {
        short8 kf = *(const short8*)(Kl + row * 256 + (((kc * 4 + g) ^ (row & 15)) << 4));
#pragma unroll
        for (int nt = 0; nt < 4; nt++)
          sf[mt][nt] = __builtin_amdgcn_mfma_f32_16x16x32_bf16(kf, qf[nt][kc], sf[mt][nt], 0, 0, 0);
      }
    }

    // ---- p = exp2(s); P^T C-layout (4 consecutive kv per lane) -> b64 writes ----
#pragma unroll
    for (int mt = 0; mt < 4; mt++)
#pragma unroll
      for (int nt = 0; nt < 4; nt++) {
        ushort4 p;
        p.x = f2bf(EXP2(sf[mt][nt][0]));
        p.y = f2bf(EXP2(sf[mt][nt][1]));
        p.z = f2bf(EXP2(sf[mt][nt][2]));
        p.w = f2bf(EXP2(sf[mt][nt][3]));
        // q = nt*16+r ; kv bytes mt*32+g*8 -> chunk 2mt+(g>>1), half g&1
        int q  = nt * 16 + r;
        int ch = (2 * mt + (g >> 1)) ^ (r & 7);
        *(ushort4*)(Pl + q * 128 + ch * 16 + (g & 1) * 8) = p;
      }
    // A-frags of P: m=q=r(+16nt), k=kv=c2*32+g*8+j -> chunk c2*4+g
    short8 pf[4][2];
#pragma unroll
    for (int nt = 0; nt < 4; nt++)
#pragma unroll
      for (int c2 = 0; c2 < 2; c2++) {
        int q = nt * 16 + r;
        pf[nt][c2] = *(const short8*)(Pl + q * 128 + (((c2 * 4 + g) ^ (r & 7)) << 4));
      }

    // ---- O += P V ; l += P @ ones ----
#pragma unroll
    for (int dg = 0; dg < 8; dg++) {
      int d = dg * 16 + r;
#pragma unroll
      for (int c2 = 0; c2 < 2; c2++) {
        short8 vf = *(const short8*)(Vl + d * 128 + (((c2 * 4 + g) ^ (d & 7)) << 4));
#pragma unroll
        for (int nt = 0; nt < 4; nt++)
          oacc[nt][dg] = __builtin_amdgcn_mfma_f32_16x16x32_bf16(pf[nt][c2], vf, oacc[nt][dg], 0, 0, 0);
      }
    }
#pragma unroll
    for (int nt = 0; nt < 4; nt++) {
      lacc[nt] = __builtin_amdgcn_mfma_f32_16x16x32_bf16(pf[nt][0], onesf, lacc[nt], 0, 0, 0);
      lacc[nt] = __builtin_amdgcn_mfma_f32_16x16x32_bf16(pf[nt][1], onesf, lacc[nt], 0, 0, 0);
    }
    __syncthreads();
  }

  // ---- write partials ----
  const size_t pbase = (size_t)sp * SEQ;
#pragma unroll
  for (int nt = 0; nt < 4; nt++)
#pragma unroll
    for (int rr = 0; rr < 4; rr++) {
      int q = q0 + nt * 16 + g * 4 + rr;
      float* orow = Opart + (pbase + q) * DOUT;
#pragma unroll
      for (int dg = 0; dg < 8; dg++)
        orow[dg * 16 + r] = oacc[nt][dg][rr];
      if (r == 0) lpart[pbase + q] = lacc[nt][rr];
    }
}

// ---------------------------------------------------------------------------
// Kernel C: combine 8 KV-split partials (plain sum + normalize).
// ---------------------------------------------------------------------------
__global__ void combine_kernel(const float* __restrict__ Opart,
                               const float* __restrict__ lpart,
                               float* __restrict__ out) {
  int idx = blockIdx.x * 256 + threadIdx.x;  // 8192*32
  int s   = idx >> 5;
  int d4  = (idx & 31) * 4;
  float L = 0.f;
  f32x4 acc = 0.f;
#pragma unroll
  for (int p = 0; p < 8; p++) {
    L += lpart[p * SEQ + s];
    acc += *(const f32x4*)(Opart + ((size_t)p * SEQ + s) * DOUT + d4);
  }
  f32x4 res = acc * (1.0f / L);
  *(f32x4*)(out + (size_t)s * DOUT + d4) = res;
}

// ---------------------------------------------------------------------------
extern "C" void kernel_launch(void* const* d_in, const int* in_sizes, int n_in,
                              void* d_out, int out_size, void* d_ws, size_t ws_size,
                              hipStream_t stream) {
  const float* x  = (const float*)d_in[0];
  const float* wq = (const float*)d_in[1];
  const float* wk = (const float*)d_in[2];
  const float* wv = (const float*)d_in[3];
  float* out = (float*)d_out;

  unsigned short* Qb  = (unsigned short*)d_ws;            // 2 MB
  unsigned short* Kb  = Qb + (size_t)SEQ * DOUT;          // 2 MB
  unsigned short* Vtb = Kb + (size_t)SEQ * DOUT;          // 2 MB (transposed)
  float* Opart = (float*)(Vtb + (size_t)SEQ * DOUT);      // 8 * 4 MB
  float* lpart = Opart + (size_t)8 * SEQ * DOUT;          // 256 KB
  if (ws_size < (size_t)(6291456 + 33554432 + 262144)) return;

  qkv_kernel<<<dim3(64, 3), 256, 0, stream>>>(x, wq, wk, wv, Qb, Kb, Vtb);
  attn_kernel<<<dim3(64, 8), 128, 0, stream>>>(Qb, Kb, Vtb, Opart, lpart);
  combine_kernel<<<dim3(1024), 256, 0, stream>>>(Opart, lpart, out);
}